// Round 16
// baseline (737.881 us; speedup 1.0000x reference)
//
#include <hip/hip_runtime.h>
#include <hip/hip_bf16.h>
#include <math.h>

#define N_NODES 200000
#define N_E     400000
#define N_H     400000
#define N_M     800000
#define HK3     1200000   // N_H * K_HYP
#define DIM_N   128
#define K_EDGE  32
#define D1      296       // 128+32+8+64+64
#define KX      320       // D1 padded to multiple of 32
#define LN_EPS  1e-3f
#define TILE    32
#define CHUNK   1024
#define NCH     196       // ceil(200000/1024)
#define NB_E    12500     // mh blocks for edges
#define NB_N    6250      // mh blocks for nodes
#define NB_C    7813      // count blocks: ceil((HK3+N_M)/256)

typedef __attribute__((ext_vector_type(8))) short bf16x8;
typedef __attribute__((ext_vector_type(4))) float f32x4;
typedef unsigned short ushort_t;

#define SWZ(rr) (((rr) & 7) << 4)

__device__ __forceinline__ short f2bf(float f) {
    unsigned u = __float_as_uint(f);
    unsigned r = (u + 0x7fffu + ((u >> 16) & 1u)) >> 16;
    return (short)r;
}
__device__ __forceinline__ float bf2f(ushort_t u) {
    return __uint_as_float(((unsigned)u) << 16);
}
__device__ __forceinline__ void split2(float v, short& hi, short& lo) {
    hi = f2bf(v);
    float r = v - __uint_as_float(((unsigned)(ushort_t)hi) << 16);
    lo = f2bf(r);
}

// ---------------- K0: fold attention weights through Conv1D tap 1 ----------------
__global__ void prep_weights(const float* __restrict__ Wq, const float* __restrict__ bq,
                             const float* __restrict__ Wk, const float* __restrict__ bk,
                             const float* __restrict__ Wc, const float* __restrict__ bc,
                             float* Wqc, float* bqc, float* Wkc, float* bkc) {
    int t = blockIdx.x * 256 + threadIdx.x;
    const float* Wc1 = Wc + 64;  // Wc[1], [8][8]
    if (t < 128 * 8) {
        int i = t >> 3, o = t & 7;
        float s = 0.f, s2 = 0.f;
        for (int a = 0; a < 8; ++a) {
            float w = Wc1[a * 8 + o];
            s  += Wq[i * 8 + a] * w;
            s2 += Wk[i * 8 + a] * w;
        }
        Wqc[t] = s;
        Wkc[t] = s2;
    } else if (t < 128 * 8 + 8) {
        int o = t - 1024;
        float s = 0.f, s2 = 0.f;
        for (int a = 0; a < 8; ++a) {
            float w = Wc1[a * 8 + o];
            s  += bq[a] * w;
            s2 += bk[a] * w;
        }
        bqc[o] = s + bc[o];
        bkc[o] = s2 + bc[o];
    }
}

// ---------------- K0b: MFMA-fragment-linear hi/lo weight layout (round-8-proven) ----------------
__global__ void prep_wF(const float* __restrict__ W1, const float* __restrict__ W2,
                        short* __restrict__ W1Fh, short* __restrict__ W1Fl,
                        short* __restrict__ W2Fh, short* __restrict__ W2Fl) {
    int g = blockIdx.x * 256 + threadIdx.x;   // 10240 (W1) + 4096 (W2) fragment-lanes
    if (g < 10240) {
        int l = g & 63, f = g >> 6;
        int s = f % 10, nt = (f / 10) & 3, wid = f / 40;
        int col = wid * 64 + nt * 16 + (l & 15);
        int k0 = s * 32 + (l >> 4) * 8;
        #pragma unroll
        for (int j = 0; j < 8; ++j) {
            int k = k0 + j;
            float w = (k < D1) ? W1[k * 256 + col] : 0.f;
            short hi, lo; split2(w, hi, lo);
            W1Fh[g * 8 + j] = hi; W1Fl[g * 8 + j] = lo;
        }
    } else if (g < 14336) {
        int u = g - 10240;
        int l = u & 63, f = u >> 6;
        int s = f & 7, nt = (f >> 3) & 1, wid = f >> 4;
        int col = wid * 32 + nt * 16 + (l & 15);
        int k0 = s * 32 + (l >> 4) * 8;
        #pragma unroll
        for (int j = 0; j < 8; ++j) {
            float w = W2[(k0 + j) * 128 + col];
            short hi, lo; split2(w, hi, lo);
            W2Fh[u * 8 + j] = hi; W2Fl[u * 8 + j] = lo;
        }
    }
}

// ---------------- mh body: out8[r][h] = bf16(feat[r] @ W(128x8) + b) ----------------
__device__ __forceinline__ void mh_body(const float* __restrict__ feat,
                                        const float* __restrict__ Wf,
                                        const float* __restrict__ bf_,
                                        ushort_t* __restrict__ out8,
                                        int blk, int tid,
                                        float* el, float* wlT, float* bl) {
    for (int i = tid; i < 1024; i += 256) {
        int h = i >> 7, k = i & 127;
        wlT[h * 132 + k] = Wf[k * 8 + h];
    }
    if (tid < 8) bl[tid] = bf_[tid];
    long e0 = (long)blk * 32;
    const float4* ep = (const float4*)feat + e0 * 32;
    for (int it = 0; it < 4; ++it) {
        int idx = it * 256 + tid;
        int e = idx >> 5, f = idx & 31;
        float4 v = ep[e * 32 + f];
        float* d = &el[e * 132 + f * 4];
        d[0] = v.x; d[1] = v.y; d[2] = v.z; d[3] = v.w;
    }
    __syncthreads();
    int e = tid >> 3, h = tid & 7;
    float acc = bl[h];
    const float* er = &el[e * 132];
    const float* wr = &wlT[h * 132];
    #pragma unroll 8
    for (int i = 0; i < 128; i += 4) {
        float4 ev = *(const float4*)&er[i];
        float4 wv = *(const float4*)&wr[i];
        acc += ev.x * wv.x + ev.y * wv.y + ev.z * wv.z + ev.w * wv.w;
    }
    out8[(e0 + e) * 8 + h] = (ushort_t)f2bf(acc);
}

// ---------------- K1 (fused): mh(edges) | mh(nodes) | count — blockIdx-uniform branch ----------------
__global__ __launch_bounds__(256) void aux1_kernel(
    const float* __restrict__ edges, const float* __restrict__ Wkc,
    const float* __restrict__ bkc, ushort_t* __restrict__ kmh,
    const float* __restrict__ nodes, const float* __restrict__ Wqc,
    const float* __restrict__ bqc, ushort_t* __restrict__ qmh,
    const int* __restrict__ hind, const int* __restrict__ mind,
    int* __restrict__ cnth, int* __restrict__ cntm)
{
    __shared__ __align__(16) float el[32 * 132];
    __shared__ __align__(16) float wlT[8 * 132];
    __shared__ float bl[8];
    int b = blockIdx.x, tid = threadIdx.x;
    if (b < NB_E) {
        mh_body(edges, Wkc, bkc, kmh, b, tid, el, wlT, bl);
    } else if (b < NB_E + NB_N) {
        mh_body(nodes, Wqc, bqc, qmh, b - NB_E, tid, el, wlT, bl);
    } else {
        int t = (b - NB_E - NB_N) * 256 + tid;
        if (t < HK3)              atomicAdd(&cnth[hind[t]], 1);
        else if (t < HK3 + N_M)   atomicAdd(&cntm[mind[t - HK3]], 1);
    }
}

// ---------------- K2a: zero int buffer ----------------
__global__ void zero_ints(int* __restrict__ p, int n) {
    int stride = gridDim.x * blockDim.x;
    for (int i = blockIdx.x * blockDim.x + threadIdx.x; i < n; i += stride) p[i] = 0;
}

// ---------------- K3a: per-chunk sums (blocks 0..195 -> h, 196..391 -> m) ----------------
__global__ __launch_bounds__(256) void sum_chunks(const int* __restrict__ cnth,
                                                  const int* __restrict__ cntm,
                                                  int* __restrict__ bsum) {
    int b = blockIdx.x;
    const int* cnt = (b < NCH) ? cnth : cntm;
    int base = ((b < NCH) ? b : b - NCH) * CHUNK;
    int tid = threadIdx.x;
    int s = 0;
    #pragma unroll
    for (int i = 0; i < 4; ++i) {
        int idx = base + i * 256 + tid;
        if (idx < N_NODES) s += cnt[idx];
    }
    __shared__ int sb[4];
    for (int d = 1; d < 64; d <<= 1) s += __shfl_xor(s, d);
    if ((tid & 63) == 0) sb[tid >> 6] = s;
    __syncthreads();
    if (tid == 0) bsum[b] = sb[0] + sb[1] + sb[2] + sb[3];
}

// ---------------- K3b: exclusive scan of the 2x196 chunk sums (in place) ----------------
__global__ __launch_bounds__(256) void scan_sums(int* __restrict__ bsum) {
    __shared__ int sh[2][256];
    int tid = threadIdx.x;
    sh[0][tid] = (tid < NCH) ? bsum[tid] : 0;
    sh[1][tid] = (tid < NCH) ? bsum[NCH + tid] : 0;
    __syncthreads();
    for (int d = 1; d < 256; d <<= 1) {
        int v0 = (tid >= d) ? sh[0][tid - d] : 0;
        int v1 = (tid >= d) ? sh[1][tid - d] : 0;
        __syncthreads();
        sh[0][tid] += v0; sh[1][tid] += v1;
        __syncthreads();
    }
    if (tid < NCH) {
        bsum[tid]       = tid ? sh[0][tid - 1] : 0;
        bsum[NCH + tid] = tid ? sh[1][tid - 1] : 0;
    }
}

// ---------------- K3c: per-chunk exclusive scan -> off/woff (coalesced) ----------------
__global__ __launch_bounds__(256) void scan_chunks(const int* __restrict__ cnth,
                                                   const int* __restrict__ cntm,
                                                   const int* __restrict__ bsum,
                                                   int* __restrict__ offh, int* __restrict__ woffh,
                                                   int* __restrict__ offm, int* __restrict__ woffm) {
    int b = blockIdx.x;
    bool ish = (b < NCH);
    const int* cnt = ish ? cnth : cntm;
    int c = ish ? b : b - NCH;
    int* off  = ish ? offh  : offm;
    int* woff = ish ? woffh : woffm;
    int base = c * CHUNK;
    int tid = threadIdx.x;
    __shared__ int lds[CHUNK];
    __shared__ int tsum[256];
    #pragma unroll
    for (int i = 0; i < 4; ++i) {
        int idx = base + i * 256 + tid;
        lds[i * 256 + tid] = (idx < N_NODES) ? cnt[idx] : 0;
    }
    __syncthreads();
    int v0 = lds[tid * 4], v1 = lds[tid * 4 + 1], v2 = lds[tid * 4 + 2], v3 = lds[tid * 4 + 3];
    int tot = v0 + v1 + v2 + v3;
    tsum[tid] = tot;
    __syncthreads();
    for (int d = 1; d < 256; d <<= 1) {
        int v = (tid >= d) ? tsum[tid - d] : 0;
        __syncthreads();
        tsum[tid] += v;
        __syncthreads();
    }
    int pre = tsum[tid] - tot + bsum[b];
    int4 o;
    o.x = pre; o.y = pre + v0; o.z = pre + v0 + v1; o.w = pre + v0 + v1 + v2;
    int idx = base + tid * 4;
    if (idx + 3 < N_NODES) {
        *(int4*)(off + idx)  = o;
        *(int4*)(woff + idx) = o;
    } else {
        if (idx     < N_NODES) { off[idx]     = o.x; woff[idx]     = o.x; }
        if (idx + 1 < N_NODES) { off[idx + 1] = o.y; woff[idx + 1] = o.y; }
        if (idx + 2 < N_NODES) { off[idx + 2] = o.z; woff[idx + 2] = o.z; }
        if (idx + 3 < N_NODES) { off[idx + 3] = o.w; woff[idx + 3] = o.w; }
    }
}

// ---------------- K4: fill CSR lists (int4-vectorized; woff becomes end offset) ----------------
__global__ __launch_bounds__(256) void fill_kernel(
    const int* __restrict__ hind, const int* __restrict__ mind,
    int* __restrict__ woffh, int* __restrict__ woffm,
    int* __restrict__ listh, int* __restrict__ listm) {
    int t = blockIdx.x * 256 + threadIdx.x;
    if (t < HK3 / 4) {
        int4 nd = ((const int4*)hind)[t];
        int base = t * 4;
        int p0 = atomicAdd(&woffh[nd.x], 1); listh[p0] = (base    ) / 3;
        int p1 = atomicAdd(&woffh[nd.y], 1); listh[p1] = (base + 1) / 3;
        int p2 = atomicAdd(&woffh[nd.z], 1); listh[p2] = (base + 2) / 3;
        int p3 = atomicAdd(&woffh[nd.w], 1); listh[p3] = (base + 3) / 3;
    } else if (t < HK3 / 4 + N_M / 4) {
        int u = t - HK3 / 4;
        int4 nd = ((const int4*)mind)[u];
        int base = u * 4;
        int p0 = atomicAdd(&woffm[nd.x], 1); listm[p0] = base;
        int p1 = atomicAdd(&woffm[nd.y], 1); listm[p1] = base + 1;
        int p2 = atomicAdd(&woffm[nd.z], 1); listm[p2] = base + 2;
        int p3 = atomicAdd(&woffm[nd.w], 1); listm[p3] = base + 3;
    }
}

// ---------------- K6: fused CSR-gather + attention + split-precision MFMA MLP + LN ----------------
// Round-15 kernel with: (a) h/m gather streams INTERLEAVED (dual 4-way, per-stream
// order unchanged -> bitwise-identical), (b) s_setprio(1) around MFMA clusters.
// Attention / staging / pad / eind / LN byte-identical to passing round 15.
__global__ __launch_bounds__(256) void main_kernel(
    const float* __restrict__ nodes, const float* __restrict__ globals_,
    const int* __restrict__ n_node, const int* __restrict__ edge_ind,
    const ushort_t* __restrict__ kmh, const ushort_t* __restrict__ qmh,
    const float* __restrict__ hfeat, const int* __restrict__ offh,
    const int* __restrict__ woffh, const int* __restrict__ listh,
    const float* __restrict__ mfeat, const int* __restrict__ offm,
    const int* __restrict__ woffm, const int* __restrict__ listm,
    const short* __restrict__ W1Fh, const short* __restrict__ W1Fl, const float* __restrict__ b1,
    const short* __restrict__ W2Fh, const short* __restrict__ W2Fl, const float* __restrict__ b2,
    const float* __restrict__ ln_g, const float* __restrict__ ln_b,
    float* __restrict__ out)
{
    __shared__ __align__(16) char buf[20480];   // x bf16 [32][640B] -> h1 bf16 [32][512B] -> h2 f32
    __shared__ int eind[32 * 33];
    __shared__ float mrs[64];

    int tid = threadIdx.x;
    int n0 = blockIdx.x * TILE;
    char* xhi = buf;

    // --- stage nodes -> cols 0..127 ---
    const float4* np4 = (const float4*)nodes;
    #pragma unroll
    for (int it = 0; it < 4; ++it) {
        int idx = it * 256 + tid;
        int r = idx >> 5, c4 = idx & 31;
        float4 v = np4[(size_t)(n0 + r) * 32 + c4];
        short4 hi;
        hi.x = f2bf(v.x); hi.y = f2bf(v.y); hi.z = f2bf(v.z); hi.w = f2bf(v.w);
        *(short4*)(xhi + r * 640 + ((c4 * 8) ^ SWZ(r))) = hi;
    }
    // --- stage globals -> cols 128..159 ---
    {
        int nn0 = n_node[0];
        int r = tid >> 3, c4 = tid & 7;
        int gid = (n0 + r) / nn0;
        float4 v = ((const float4*)globals_)[gid * 8 + c4];
        short4 hi;
        hi.x = f2bf(v.x); hi.y = f2bf(v.y); hi.z = f2bf(v.z); hi.w = f2bf(v.w);
        *(short4*)(xhi + r * 640 + ((256 + c4 * 8) ^ SWZ(r))) = hi;
    }
    // --- fused CSR gathers: 8 threads/row, h+m streams interleaved for MLP ---
    {
        int r = tid >> 3, q = tid & 7;
        int n = n0 + r;
        float ah[8], am[8];
        #pragma unroll
        for (int i = 0; i < 8; ++i) { ah[i] = 0.f; am[i] = 0.f; }
        int eh = offh[n], ehe = woffh[n];
        int em = offm[n], eme = woffm[n];
        #define ACC8(A, U, V) do { \
            A[0] += (U).x; A[1] += (U).y; A[2] += (U).z; A[3] += (U).w; \
            A[4] += (V).x; A[5] += (V).y; A[6] += (V).z; A[7] += (V).w; } while (0)
        // interleaved phase: 4 h-rows + 4 m-rows in flight together
        for (; eh + 4 <= ehe && em + 4 <= eme; eh += 4, em += 4) {
            int h0 = listh[eh], h1_ = listh[eh + 1], h2_ = listh[eh + 2], h3 = listh[eh + 3];
            int m0 = listm[em], m1 = listm[em + 1], m2 = listm[em + 2], m3 = listm[em + 3];
            const float4* ph0 = (const float4*)(hfeat + (size_t)h0  * 64 + q * 8);
            const float4* ph1 = (const float4*)(hfeat + (size_t)h1_ * 64 + q * 8);
            const float4* ph2 = (const float4*)(hfeat + (size_t)h2_ * 64 + q * 8);
            const float4* ph3 = (const float4*)(hfeat + (size_t)h3  * 64 + q * 8);
            const float4* pm0 = (const float4*)(mfeat + (size_t)m0 * 64 + q * 8);
            const float4* pm1 = (const float4*)(mfeat + (size_t)m1 * 64 + q * 8);
            const float4* pm2 = (const float4*)(mfeat + (size_t)m2 * 64 + q * 8);
            const float4* pm3 = (const float4*)(mfeat + (size_t)m3 * 64 + q * 8);
            float4 hu0 = ph0[0], hv0 = ph0[1], hu1 = ph1[0], hv1 = ph1[1];
            float4 hu2 = ph2[0], hv2 = ph2[1], hu3 = ph3[0], hv3 = ph3[1];
            float4 mu0 = pm0[0], mv0 = pm0[1], mu1 = pm1[0], mv1 = pm1[1];
            float4 mu2 = pm2[0], mv2 = pm2[1], mu3 = pm3[0], mv3 = pm3[1];
            ACC8(ah, hu0, hv0); ACC8(ah, hu1, hv1); ACC8(ah, hu2, hv2); ACC8(ah, hu3, hv3);
            ACC8(am, mu0, mv0); ACC8(am, mu1, mv1); ACC8(am, mu2, mv2); ACC8(am, mu3, mv3);
        }
        // drain h (4-way then tail)
        for (; eh + 4 <= ehe; eh += 4) {
            int h0 = listh[eh], h1_ = listh[eh + 1], h2_ = listh[eh + 2], h3 = listh[eh + 3];
            const float4* p0 = (const float4*)(hfeat + (size_t)h0  * 64 + q * 8);
            const float4* p1 = (const float4*)(hfeat + (size_t)h1_ * 64 + q * 8);
            const float4* p2 = (const float4*)(hfeat + (size_t)h2_ * 64 + q * 8);
            const float4* p3 = (const float4*)(hfeat + (size_t)h3  * 64 + q * 8);
            float4 u0 = p0[0], v0 = p0[1], u1 = p1[0], v1 = p1[1];
            float4 u2 = p2[0], v2 = p2[1], u3 = p3[0], v3 = p3[1];
            ACC8(ah, u0, v0); ACC8(ah, u1, v1); ACC8(ah, u2, v2); ACC8(ah, u3, v3);
        }
        for (; eh < ehe; ++eh) {
            const float4* p = (const float4*)(hfeat + (size_t)listh[eh] * 64 + q * 8);
            float4 u = p[0], v = p[1];
            ACC8(ah, u, v);
        }
        // drain m (4-way then tail)
        for (; em + 4 <= eme; em += 4) {
            int m0 = listm[em], m1 = listm[em + 1], m2 = listm[em + 2], m3 = listm[em + 3];
            const float4* p0 = (const float4*)(mfeat + (size_t)m0 * 64 + q * 8);
            const float4* p1 = (const float4*)(mfeat + (size_t)m1 * 64 + q * 8);
            const float4* p2 = (const float4*)(mfeat + (size_t)m2 * 64 + q * 8);
            const float4* p3 = (const float4*)(mfeat + (size_t)m3 * 64 + q * 8);
            float4 u0 = p0[0], v0 = p0[1], u1 = p1[0], v1 = p1[1];
            float4 u2 = p2[0], v2 = p2[1], u3 = p3[0], v3 = p3[1];
            ACC8(am, u0, v0); ACC8(am, u1, v1); ACC8(am, u2, v2); ACC8(am, u3, v3);
        }
        for (; em < eme; ++em) {
            const float4* p = (const float4*)(mfeat + (size_t)listm[em] * 64 + q * 8);
            float4 u = p[0], v = p[1];
            ACC8(am, u, v);
        }
        #undef ACC8
        {
            bf16x8 hi;
            #pragma unroll
            for (int i = 0; i < 8; ++i) hi[i] = f2bf(ah[i]);
            *(bf16x8*)(xhi + r * 640 + ((336 + q * 16) ^ SWZ(r))) = hi;
            #pragma unroll
            for (int i = 0; i < 8; ++i) hi[i] = f2bf(am[i]);
            *(bf16x8*)(xhi + r * 640 + ((464 + q * 16) ^ SWZ(r))) = hi;
        }
    }
    // --- zero pad cols 296..319 (essential: stale LDS can decode as bf16 Inf/NaN) ---
    if (tid < 192) {
        short4 z = { 0, 0, 0, 0 };
        int r = tid / 6, j = tid % 6;
        *(short4*)(xhi + r * 640 + ((592 + j * 8) ^ SWZ(r))) = z;
    }
    // --- stage edge indices ---
    #pragma unroll
    for (int it = 0; it < 4; ++it) {
        int idx = it * 256 + tid;
        int r = idx >> 5, j = idx & 31;
        eind[r * 33 + j] = edge_ind[(size_t)(n0 + r) * 32 + j];
    }
    __syncthreads();

    // --- edge attention (online softmax, LDS eind — load-bearing; byte-identical to R15) ---
    {
        int r = tid & 31, h = tid >> 5;
        float qv = bf2f(qmh[(size_t)(n0 + r) * 8 + h]);
        float m = -INFINITY, s = 0.f, wv = 0.f;
        for (int j = 0; j < K_EDGE; ++j) {
            int e = eind[r * 33 + j];
            float v = bf2f(kmh[(size_t)e * 8 + h]);
            float l = qv * v;
            float mn = fmaxf(m, l);
            float fac = __expf(m - mn);
            float p = __expf(l - mn);
            s = s * fac + p;
            wv = wv * fac + p * v;
            m = mn;
        }
        *(short*)(xhi + r * 640 + ((320 + h * 2) ^ SWZ(r))) = f2bf(wv / s);
    }
    __syncthreads();

    // --- h1 = relu(x @ W1 + b1), 2-pass split MFMA: M=32, N=256, K=320 ---
    int wid = tid >> 6, lane = tid & 63;
    int arow = lane & 15, kgrp = lane >> 4;
    f32x4 c1[2][4];
    #pragma unroll
    for (int mt = 0; mt < 2; ++mt)
        #pragma unroll
        for (int nt = 0; nt < 4; ++nt)
            c1[mt][nt] = (f32x4){0.f, 0.f, 0.f, 0.f};
    const bf16x8* w1h = (const bf16x8*)W1Fh;
    const bf16x8* w1l = (const bf16x8*)W1Fl;
    __builtin_amdgcn_s_setprio(1);
    for (int s = 0; s < 10; ++s) {
        int kb = (s * 32 + kgrp * 8) * 2;
        bf16x8 ahv[2], bh[4], bl[4];
        #pragma unroll
        for (int mt = 0; mt < 2; ++mt) {
            int rr = mt * 16 + arow;
            ahv[mt] = *(const bf16x8*)(xhi + rr * 640 + (kb ^ SWZ(rr)));
        }
        #pragma unroll
        for (int nt = 0; nt < 4; ++nt) {
            size_t fi = ((size_t)(wid * 4 + nt) * 10 + s) * 64 + lane;
            bh[nt] = w1h[fi];
            bl[nt] = w1l[fi];
        }
        #pragma unroll
        for (int mt = 0; mt < 2; ++mt)
            #pragma unroll
            for (int nt = 0; nt < 4; ++nt) {
                c1[mt][nt] = __builtin_amdgcn_mfma_f32_16x16x32_bf16(ahv[mt], bh[nt], c1[mt][nt], 0, 0, 0);
                c1[mt][nt] = __builtin_amdgcn_mfma_f32_16x16x32_bf16(ahv[mt], bl[nt], c1[mt][nt], 0, 0, 0);
            }
    }
    __builtin_amdgcn_s_setprio(0);
    __syncthreads();
    // store h1 SINGLE bf16 plane [32][256], stride 512B
    char* h1p = buf;
    #pragma unroll
    for (int nt = 0; nt < 4; ++nt) {
        int col = wid * 64 + nt * 16 + arow;
        float bb = b1[col];
        #pragma unroll
        for (int mt = 0; mt < 2; ++mt)
            #pragma unroll
            for (int i = 0; i < 4; ++i) {
                int rr = mt * 16 + kgrp * 4 + i;
                float v = fmaxf(c1[mt][nt][i] + bb, 0.f);
                *(short*)(h1p + rr * 512 + ((col * 2) ^ SWZ(rr))) = f2bf(v);
            }
    }
    __syncthreads();

    // --- h2 = relu(h1 @ W2 + b2), 2-pass split MFMA: M=32, N=128, K=256 ---
    f32x4 c2[2][2];
    #pragma unroll
    for (int mt = 0; mt < 2; ++mt)
        #pragma unroll
        for (int nt = 0; nt < 2; ++nt)
            c2[mt][nt] = (f32x4){0.f, 0.f, 0.f, 0.f};
    const bf16x8* w2h = (const bf16x8*)W2Fh;
    const bf16x8* w2l = (const bf16x8*)W2Fl;
    __builtin_amdgcn_s_setprio(1);
    for (int s = 0; s < 8; ++s) {
        int kb = (s * 32 + kgrp * 8) * 2;
        bf16x8 ahv[2], bh[2], bl[2];
        #pragma unroll
        for (int mt = 0; mt < 2; ++mt) {
            int rr = mt * 16 + arow;
            ahv[mt] = *(const bf16x8*)(h1p + rr * 512 + (kb ^ SWZ(rr)));
        }
        #pragma unroll
        for (int nt = 0; nt < 2; ++nt) {
            size_t fi = ((size_t)(wid * 2 + nt) * 8 + s) * 64 + lane;
            bh[nt] = w2h[fi];
            bl[nt] = w2l[fi];
        }
        #pragma unroll
        for (int mt = 0; mt < 2; ++mt)
            #pragma unroll
            for (int nt = 0; nt < 2; ++nt) {
                c2[mt][nt] = __builtin_amdgcn_mfma_f32_16x16x32_bf16(ahv[mt], bh[nt], c2[mt][nt], 0, 0, 0);
                c2[mt][nt] = __builtin_amdgcn_mfma_f32_16x16x32_bf16(ahv[mt], bl[nt], c2[mt][nt], 0, 0, 0);
            }
    }
    __builtin_amdgcn_s_setprio(0);
    __syncthreads();
    // store h2 f32 [32][132], stride 528B
    #pragma unroll
    for (int nt = 0; nt < 2; ++nt) {
        int col = wid * 32 + nt * 16 + arow;
        float bb = b2[col];
        #pragma unroll
        for (int mt = 0; mt < 2; ++mt)
            #pragma unroll
            for (int i = 0; i < 4; ++i) {
                int rr = mt * 16 + kgrp * 4 + i;
                *(float*)(buf + rr * 528 + col * 4) = fmaxf(c2[mt][nt][i] + bb, 0.f);
            }
    }
    __syncthreads();

    // --- LayerNorm stats: 8 threads per row ---
    {
        int r = tid >> 3, q = tid & 7;
        const float* row = (const float*)(buf + r * 528) + q * 16;
        float s = 0.f, sq = 0.f;
        #pragma unroll
        for (int j = 0; j < 4; ++j) {
            float4 v = *(const float4*)(row + j * 4);
            s  += v.x + v.y + v.z + v.w;
            sq += v.x * v.x + v.y * v.y + v.z * v.z + v.w * v.w;
        }
        s  += __shfl_xor(s, 1);  sq += __shfl_xor(sq, 1);
        s  += __shfl_xor(s, 2);  sq += __shfl_xor(sq, 2);
        s  += __shfl_xor(s, 4);  sq += __shfl_xor(sq, 4);
        if (q == 0) {
            float mean = s * (1.f / 128.f);
            float var = sq * (1.f / 128.f) - mean * mean;
            mrs[r] = mean;
            mrs[32 + r] = rsqrtf(var + LN_EPS);
        }
    }
    __syncthreads();
    // --- normalize + affine + coalesced store ---
    #pragma unroll
    for (int it = 0; it < 4; ++it) {
        int idx = it * 256 + tid;
        int r = idx >> 5, c4 = idx & 31;
        float4 v = *(const float4*)(buf + r * 528 + c4 * 16);
        float mu = mrs[r], rs = mrs[32 + r];
        float4 g = ((const float4*)ln_g)[c4];
        float4 bb = ((const float4*)ln_b)[c4];
        float4 o;
        o.x = (v.x - mu) * rs * g.x + bb.x;
        o.y = (v.y - mu) * rs * g.y + bb.y;
        o.z = (v.z - mu) * rs * g.z + bb.z;
        o.w = (v.w - mu) * rs * g.w + bb.w;
        ((float4*)out)[(size_t)(n0 + r) * 32 + c4] = o;
    }
}

extern "C" void kernel_launch(void* const* d_in, const int* in_sizes, int n_in,
                              void* d_out, int out_size, void* d_ws, size_t ws_size,
                              hipStream_t stream) {
    const float* nodes    = (const float*)d_in[0];
    const float* globals_ = (const float*)d_in[1];
    const int*   n_node   = (const int*)  d_in[2];
    const float* edges    = (const float*)d_in[3];
    const int*   edge_ind = (const int*)  d_in[4];
    const float* hfeat    = (const float*)d_in[5];
    const int*   hind     = (const int*)  d_in[6];
    const float* mfeat    = (const float*)d_in[7];
    const int*   mind     = (const int*)  d_in[8];
    const float* Wq       = (const float*)d_in[9];
    const float* bq       = (const float*)d_in[10];
    const float* Wk       = (const float*)d_in[11];
    const float* bk       = (const float*)d_in[12];
    const float* Wc       = (const float*)d_in[13];
    const float* bc       = (const float*)d_in[14];
    const float* W1       = (const float*)d_in[15];
    const float* b1       = (const float*)d_in[16];
    const float* W2       = (const float*)d_in[17];
    const float* b2       = (const float*)d_in[18];
    const float* ln_g     = (const float*)d_in[19];
    const float* ln_b     = (const float*)d_in[20];
    float* out = (float*)d_out;

    char* w = (char*)d_ws;
    size_t off = 0;
    auto take = [&](size_t bytes) -> char* {
        char* p = w + off;
        off = (off + bytes + 255) & ~(size_t)255;
        return p;
    };
    float*    Wqc  = (float*)take(1024 * 4);
    float*    bqc  = (float*)take(8 * 4);
    float*    Wkc  = (float*)take(1024 * 4);
    float*    bkc  = (float*)take(8 * 4);
    short*    W1Fh = (short*)take(256 * KX * 2);
    short*    W1Fl = (short*)take(256 * KX * 2);
    short*    W2Fh = (short*)take(128 * 256 * 2);
    short*    W2Fl = (short*)take(128 * 256 * 2);
    ushort_t* kmh  = (ushort_t*)take((size_t)N_E * 8 * 2);
    ushort_t* qmh  = (ushort_t*)take((size_t)N_NODES * 8 * 2);
    int*      cnth = (int*)take((size_t)N_NODES * 4);
    int*      cntm = (int*)take((size_t)N_NODES * 4);   // contiguous with cnth
    int*      offh = (int*)take((size_t)N_NODES * 4);
    int*      woffh= (int*)take((size_t)N_NODES * 4);
    int*      offm = (int*)take((size_t)N_NODES * 4);
    int*      woffm= (int*)take((size_t)N_NODES * 4);
    int*      listh= (int*)take((size_t)HK3 * 4);
    int*      listm= (int*)take((size_t)N_M * 4);
    int*      bsum = (int*)take(2 * NCH * 4);
    (void)ws_size;

    prep_weights<<<5, 256, 0, stream>>>(Wq, bq, Wk, bk, Wc, bc, Wqc, bqc, Wkc, bkc);
    prep_wF<<<56, 256, 0, stream>>>(W1, W2, W1Fh, W1Fl, W2Fh, W2Fl);
    zero_ints<<<512, 256, 0, stream>>>(cnth, 2 * N_NODES);   // cnth+cntm contiguous
    aux1_kernel<<<NB_E + NB_N + NB_C, 256, 0, stream>>>(
        edges, Wkc, bkc, kmh, nodes, Wqc, bqc, qmh, hind, mind, cnth, cntm);
    sum_chunks<<<2 * NCH, 256, 0, stream>>>(cnth, cntm, bsum);
    scan_sums<<<1, 256, 0, stream>>>(bsum);
    scan_chunks<<<2 * NCH, 256, 0, stream>>>(cnth, cntm, bsum, offh, woffh, offm, woffm);
    fill_kernel<<<(HK3 / 4 + N_M / 4 + 255) / 256, 256, 0, stream>>>(
        hind, mind, woffh, woffm, listh, listm);
    main_kernel<<<N_NODES / TILE, 256, 0, stream>>>(
        nodes, globals_, n_node, edge_ind, kmh, qmh,
        hfeat, offh, woffh, listh, mfeat, offm, woffm, listm,
        W1Fh, W1Fl, b1, W2Fh, W2Fl, b2, ln_g, ln_b, out);
}

// Round 17
// 672.592 us; speedup vs baseline: 1.0971x; 1.0971x over previous
//
#include <hip/hip_runtime.h>
#include <hip/hip_bf16.h>
#include <math.h>

#define N_NODES 200000
#define N_E     400000
#define N_H     400000
#define N_M     800000
#define HK3     1200000   // N_H * K_HYP
#define DIM_N   128
#define K_EDGE  32
#define D1      296       // 128+32+8+64+64
#define KX      320       // D1 padded to multiple of 32
#define LN_EPS  1e-3f
#define TILE    32
#define CHUNK   1024
#define NCH     196       // ceil(200000/1024)
#define NB_E    12500     // mh blocks for edges
#define NB_N    6250      // mh blocks for nodes
#define NB_C    7813      // count blocks: ceil((HK3+N_M)/256)

typedef __attribute__((ext_vector_type(8))) short bf16x8;
typedef __attribute__((ext_vector_type(4))) float f32x4;
typedef unsigned short ushort_t;

#define SWZ(rr) (((rr) & 7) << 4)

__device__ __forceinline__ short f2bf(float f) {
    unsigned u = __float_as_uint(f);
    unsigned r = (u + 0x7fffu + ((u >> 16) & 1u)) >> 16;
    return (short)r;
}
__device__ __forceinline__ float bf2f(ushort_t u) {
    return __uint_as_float(((unsigned)u) << 16);
}
__device__ __forceinline__ void split2(float v, short& hi, short& lo) {
    hi = f2bf(v);
    float r = v - __uint_as_float(((unsigned)(ushort_t)hi) << 16);
    lo = f2bf(r);
}

// ---------------- K0: fold attention weights through Conv1D tap 1 ----------------
__global__ void prep_weights(const float* __restrict__ Wq, const float* __restrict__ bq,
                             const float* __restrict__ Wk, const float* __restrict__ bk,
                             const float* __restrict__ Wc, const float* __restrict__ bc,
                             float* Wqc, float* bqc, float* Wkc, float* bkc) {
    int t = blockIdx.x * 256 + threadIdx.x;
    const float* Wc1 = Wc + 64;  // Wc[1], [8][8]
    if (t < 128 * 8) {
        int i = t >> 3, o = t & 7;
        float s = 0.f, s2 = 0.f;
        for (int a = 0; a < 8; ++a) {
            float w = Wc1[a * 8 + o];
            s  += Wq[i * 8 + a] * w;
            s2 += Wk[i * 8 + a] * w;
        }
        Wqc[t] = s;
        Wkc[t] = s2;
    } else if (t < 128 * 8 + 8) {
        int o = t - 1024;
        float s = 0.f, s2 = 0.f;
        for (int a = 0; a < 8; ++a) {
            float w = Wc1[a * 8 + o];
            s  += bq[a] * w;
            s2 += bk[a] * w;
        }
        bqc[o] = s + bc[o];
        bkc[o] = s2 + bc[o];
    }
}

// ---------------- K0b: MFMA-fragment-linear hi/lo weight layout (round-8-proven) ----------------
__global__ void prep_wF(const float* __restrict__ W1, const float* __restrict__ W2,
                        short* __restrict__ W1Fh, short* __restrict__ W1Fl,
                        short* __restrict__ W2Fh, short* __restrict__ W2Fl) {
    int g = blockIdx.x * 256 + threadIdx.x;   // 10240 (W1) + 4096 (W2) fragment-lanes
    if (g < 10240) {
        int l = g & 63, f = g >> 6;
        int s = f % 10, nt = (f / 10) & 3, wid = f / 40;
        int col = wid * 64 + nt * 16 + (l & 15);
        int k0 = s * 32 + (l >> 4) * 8;
        #pragma unroll
        for (int j = 0; j < 8; ++j) {
            int k = k0 + j;
            float w = (k < D1) ? W1[k * 256 + col] : 0.f;
            short hi, lo; split2(w, hi, lo);
            W1Fh[g * 8 + j] = hi; W1Fl[g * 8 + j] = lo;
        }
    } else if (g < 14336) {
        int u = g - 10240;
        int l = u & 63, f = u >> 6;
        int s = f & 7, nt = (f >> 3) & 1, wid = f >> 4;
        int col = wid * 32 + nt * 16 + (l & 15);
        int k0 = s * 32 + (l >> 4) * 8;
        #pragma unroll
        for (int j = 0; j < 8; ++j) {
            float w = W2[(k0 + j) * 128 + col];
            short hi, lo; split2(w, hi, lo);
            W2Fh[u * 8 + j] = hi; W2Fl[u * 8 + j] = lo;
        }
    }
}

// ---------------- mh body: out8[r][h] = bf16(feat[r] @ W(128x8) + b) ----------------
__device__ __forceinline__ void mh_body(const float* __restrict__ feat,
                                        const float* __restrict__ Wf,
                                        const float* __restrict__ bf_,
                                        ushort_t* __restrict__ out8,
                                        int blk, int tid,
                                        float* el, float* wlT, float* bl) {
    for (int i = tid; i < 1024; i += 256) {
        int h = i >> 7, k = i & 127;
        wlT[h * 132 + k] = Wf[k * 8 + h];
    }
    if (tid < 8) bl[tid] = bf_[tid];
    long e0 = (long)blk * 32;
    const float4* ep = (const float4*)feat + e0 * 32;
    for (int it = 0; it < 4; ++it) {
        int idx = it * 256 + tid;
        int e = idx >> 5, f = idx & 31;
        float4 v = ep[e * 32 + f];
        float* d = &el[e * 132 + f * 4];
        d[0] = v.x; d[1] = v.y; d[2] = v.z; d[3] = v.w;
    }
    __syncthreads();
    int e = tid >> 3, h = tid & 7;
    float acc = bl[h];
    const float* er = &el[e * 132];
    const float* wr = &wlT[h * 132];
    #pragma unroll 8
    for (int i = 0; i < 128; i += 4) {
        float4 ev = *(const float4*)&er[i];
        float4 wv = *(const float4*)&wr[i];
        acc += ev.x * wv.x + ev.y * wv.y + ev.z * wv.z + ev.w * wv.w;
    }
    out8[(e0 + e) * 8 + h] = (ushort_t)f2bf(acc);
}

// ---------------- K1 (fused): mh(edges) | mh(nodes) | count — blockIdx-uniform branch ----------------
__global__ __launch_bounds__(256) void aux1_kernel(
    const float* __restrict__ edges, const float* __restrict__ Wkc,
    const float* __restrict__ bkc, ushort_t* __restrict__ kmh,
    const float* __restrict__ nodes, const float* __restrict__ Wqc,
    const float* __restrict__ bqc, ushort_t* __restrict__ qmh,
    const int* __restrict__ hind, const int* __restrict__ mind,
    int* __restrict__ cnth, int* __restrict__ cntm)
{
    __shared__ __align__(16) float el[32 * 132];
    __shared__ __align__(16) float wlT[8 * 132];
    __shared__ float bl[8];
    int b = blockIdx.x, tid = threadIdx.x;
    if (b < NB_E) {
        mh_body(edges, Wkc, bkc, kmh, b, tid, el, wlT, bl);
    } else if (b < NB_E + NB_N) {
        mh_body(nodes, Wqc, bqc, qmh, b - NB_E, tid, el, wlT, bl);
    } else {
        int t = (b - NB_E - NB_N) * 256 + tid;
        if (t < HK3)              atomicAdd(&cnth[hind[t]], 1);
        else if (t < HK3 + N_M)   atomicAdd(&cntm[mind[t - HK3]], 1);
    }
}

// ---------------- K2a: zero int buffer ----------------
__global__ void zero_ints(int* __restrict__ p, int n) {
    int stride = gridDim.x * blockDim.x;
    for (int i = blockIdx.x * blockDim.x + threadIdx.x; i < n; i += stride) p[i] = 0;
}

// ---------------- K3a: per-chunk sums (blocks 0..195 -> h, 196..391 -> m) ----------------
__global__ __launch_bounds__(256) void sum_chunks(const int* __restrict__ cnth,
                                                  const int* __restrict__ cntm,
                                                  int* __restrict__ bsum) {
    int b = blockIdx.x;
    const int* cnt = (b < NCH) ? cnth : cntm;
    int base = ((b < NCH) ? b : b - NCH) * CHUNK;
    int tid = threadIdx.x;
    int s = 0;
    #pragma unroll
    for (int i = 0; i < 4; ++i) {
        int idx = base + i * 256 + tid;
        if (idx < N_NODES) s += cnt[idx];
    }
    __shared__ int sb[4];
    for (int d = 1; d < 64; d <<= 1) s += __shfl_xor(s, d);
    if ((tid & 63) == 0) sb[tid >> 6] = s;
    __syncthreads();
    if (tid == 0) bsum[b] = sb[0] + sb[1] + sb[2] + sb[3];
}

// ---------------- K3b: exclusive scan of the 2x196 chunk sums (in place) ----------------
__global__ __launch_bounds__(256) void scan_sums(int* __restrict__ bsum) {
    __shared__ int sh[2][256];
    int tid = threadIdx.x;
    sh[0][tid] = (tid < NCH) ? bsum[tid] : 0;
    sh[1][tid] = (tid < NCH) ? bsum[NCH + tid] : 0;
    __syncthreads();
    for (int d = 1; d < 256; d <<= 1) {
        int v0 = (tid >= d) ? sh[0][tid - d] : 0;
        int v1 = (tid >= d) ? sh[1][tid - d] : 0;
        __syncthreads();
        sh[0][tid] += v0; sh[1][tid] += v1;
        __syncthreads();
    }
    if (tid < NCH) {
        bsum[tid]       = tid ? sh[0][tid - 1] : 0;
        bsum[NCH + tid] = tid ? sh[1][tid - 1] : 0;
    }
}

// ---------------- K3c: per-chunk exclusive scan -> off/woff (coalesced) ----------------
__global__ __launch_bounds__(256) void scan_chunks(const int* __restrict__ cnth,
                                                   const int* __restrict__ cntm,
                                                   const int* __restrict__ bsum,
                                                   int* __restrict__ offh, int* __restrict__ woffh,
                                                   int* __restrict__ offm, int* __restrict__ woffm) {
    int b = blockIdx.x;
    bool ish = (b < NCH);
    const int* cnt = ish ? cnth : cntm;
    int c = ish ? b : b - NCH;
    int* off  = ish ? offh  : offm;
    int* woff = ish ? woffh : woffm;
    int base = c * CHUNK;
    int tid = threadIdx.x;
    __shared__ int lds[CHUNK];
    __shared__ int tsum[256];
    #pragma unroll
    for (int i = 0; i < 4; ++i) {
        int idx = base + i * 256 + tid;
        lds[i * 256 + tid] = (idx < N_NODES) ? cnt[idx] : 0;
    }
    __syncthreads();
    int v0 = lds[tid * 4], v1 = lds[tid * 4 + 1], v2 = lds[tid * 4 + 2], v3 = lds[tid * 4 + 3];
    int tot = v0 + v1 + v2 + v3;
    tsum[tid] = tot;
    __syncthreads();
    for (int d = 1; d < 256; d <<= 1) {
        int v = (tid >= d) ? tsum[tid - d] : 0;
        __syncthreads();
        tsum[tid] += v;
        __syncthreads();
    }
    int pre = tsum[tid] - tot + bsum[b];
    int4 o;
    o.x = pre; o.y = pre + v0; o.z = pre + v0 + v1; o.w = pre + v0 + v1 + v2;
    int idx = base + tid * 4;
    if (idx + 3 < N_NODES) {
        *(int4*)(off + idx)  = o;
        *(int4*)(woff + idx) = o;
    } else {
        if (idx     < N_NODES) { off[idx]     = o.x; woff[idx]     = o.x; }
        if (idx + 1 < N_NODES) { off[idx + 1] = o.y; woff[idx + 1] = o.y; }
        if (idx + 2 < N_NODES) { off[idx + 2] = o.z; woff[idx + 2] = o.z; }
        if (idx + 3 < N_NODES) { off[idx + 3] = o.w; woff[idx + 3] = o.w; }
    }
}

// ---------------- K4: fill CSR lists (int4-vectorized; woff becomes end offset) ----------------
__global__ __launch_bounds__(256) void fill_kernel(
    const int* __restrict__ hind, const int* __restrict__ mind,
    int* __restrict__ woffh, int* __restrict__ woffm,
    int* __restrict__ listh, int* __restrict__ listm) {
    int t = blockIdx.x * 256 + threadIdx.x;
    if (t < HK3 / 4) {
        int4 nd = ((const int4*)hind)[t];
        int base = t * 4;
        int p0 = atomicAdd(&woffh[nd.x], 1); listh[p0] = (base    ) / 3;
        int p1 = atomicAdd(&woffh[nd.y], 1); listh[p1] = (base + 1) / 3;
        int p2 = atomicAdd(&woffh[nd.z], 1); listh[p2] = (base + 2) / 3;
        int p3 = atomicAdd(&woffh[nd.w], 1); listh[p3] = (base + 3) / 3;
    } else if (t < HK3 / 4 + N_M / 4) {
        int u = t - HK3 / 4;
        int4 nd = ((const int4*)mind)[u];
        int base = u * 4;
        int p0 = atomicAdd(&woffm[nd.x], 1); listm[p0] = base;
        int p1 = atomicAdd(&woffm[nd.y], 1); listm[p1] = base + 1;
        int p2 = atomicAdd(&woffm[nd.z], 1); listm[p2] = base + 2;
        int p3 = atomicAdd(&woffm[nd.w], 1); listm[p3] = base + 3;
    }
}

// ---------------- K6: fused CSR-gather + attention + split-precision MFMA MLP + LN ----------------
// Byte-identical to the PASSING round-15 main_kernel (691 µs build):
// x single bf16 plane, 4-way sequential h then m gather, no setprio, LDS 24960.
__global__ __launch_bounds__(256) void main_kernel(
    const float* __restrict__ nodes, const float* __restrict__ globals_,
    const int* __restrict__ n_node, const int* __restrict__ edge_ind,
    const ushort_t* __restrict__ kmh, const ushort_t* __restrict__ qmh,
    const float* __restrict__ hfeat, const int* __restrict__ offh,
    const int* __restrict__ woffh, const int* __restrict__ listh,
    const float* __restrict__ mfeat, const int* __restrict__ offm,
    const int* __restrict__ woffm, const int* __restrict__ listm,
    const short* __restrict__ W1Fh, const short* __restrict__ W1Fl, const float* __restrict__ b1,
    const short* __restrict__ W2Fh, const short* __restrict__ W2Fl, const float* __restrict__ b2,
    const float* __restrict__ ln_g, const float* __restrict__ ln_b,
    float* __restrict__ out)
{
    __shared__ __align__(16) char buf[20480];   // x bf16 [32][640B] -> h1 bf16 [32][512B] -> h2 f32
    __shared__ int eind[32 * 33];
    __shared__ float mrs[64];

    int tid = threadIdx.x;
    int n0 = blockIdx.x * TILE;
    char* xhi = buf;

    // --- stage nodes -> cols 0..127 ---
    const float4* np4 = (const float4*)nodes;
    #pragma unroll
    for (int it = 0; it < 4; ++it) {
        int idx = it * 256 + tid;
        int r = idx >> 5, c4 = idx & 31;
        float4 v = np4[(size_t)(n0 + r) * 32 + c4];
        short4 hi;
        hi.x = f2bf(v.x); hi.y = f2bf(v.y); hi.z = f2bf(v.z); hi.w = f2bf(v.w);
        *(short4*)(xhi + r * 640 + ((c4 * 8) ^ SWZ(r))) = hi;
    }
    // --- stage globals -> cols 128..159 ---
    {
        int nn0 = n_node[0];
        int r = tid >> 3, c4 = tid & 7;
        int gid = (n0 + r) / nn0;
        float4 v = ((const float4*)globals_)[gid * 8 + c4];
        short4 hi;
        hi.x = f2bf(v.x); hi.y = f2bf(v.y); hi.z = f2bf(v.z); hi.w = f2bf(v.w);
        *(short4*)(xhi + r * 640 + ((256 + c4 * 8) ^ SWZ(r))) = hi;
    }
    // --- fused CSR gathers: 8 threads per row, 8 floats each -> cols 168..295 ---
    {
        int r = tid >> 3, q = tid & 7;
        int n = n0 + r;
        float a[8];
        #pragma unroll
        for (int i = 0; i < 8; ++i) a[i] = 0.f;
        int e0 = offh[n], e1 = woffh[n];
        int e = e0;
        #define ACC8(U, V) do { \
            a[0] += (U).x; a[1] += (U).y; a[2] += (U).z; a[3] += (U).w; \
            a[4] += (V).x; a[5] += (V).y; a[6] += (V).z; a[7] += (V).w; } while (0)
        for (; e + 4 <= e1; e += 4) {
            int i0 = listh[e], i1 = listh[e + 1], i2 = listh[e + 2], i3 = listh[e + 3];
            const float4* p0 = (const float4*)(hfeat + (size_t)i0 * 64 + q * 8);
            const float4* p1 = (const float4*)(hfeat + (size_t)i1 * 64 + q * 8);
            const float4* p2 = (const float4*)(hfeat + (size_t)i2 * 64 + q * 8);
            const float4* p3 = (const float4*)(hfeat + (size_t)i3 * 64 + q * 8);
            float4 u0 = p0[0], v0 = p0[1];
            float4 u1 = p1[0], v1 = p1[1];
            float4 u2 = p2[0], v2 = p2[1];
            float4 u3 = p3[0], v3 = p3[1];
            ACC8(u0, v0); ACC8(u1, v1); ACC8(u2, v2); ACC8(u3, v3);
        }
        for (; e < e1; ++e) {
            const float4* p = (const float4*)(hfeat + (size_t)listh[e] * 64 + q * 8);
            float4 u = p[0], v = p[1];
            ACC8(u, v);
        }
        {
            bf16x8 hi;
            #pragma unroll
            for (int i = 0; i < 8; ++i) hi[i] = f2bf(a[i]);
            *(bf16x8*)(xhi + r * 640 + ((336 + q * 16) ^ SWZ(r))) = hi;
        }
        #pragma unroll
        for (int i = 0; i < 8; ++i) a[i] = 0.f;
        e0 = offm[n]; e1 = woffm[n];
        e = e0;
        for (; e + 4 <= e1; e += 4) {
            int i0 = listm[e], i1 = listm[e + 1], i2 = listm[e + 2], i3 = listm[e + 3];
            const float4* p0 = (const float4*)(mfeat + (size_t)i0 * 64 + q * 8);
            const float4* p1 = (const float4*)(mfeat + (size_t)i1 * 64 + q * 8);
            const float4* p2 = (const float4*)(mfeat + (size_t)i2 * 64 + q * 8);
            const float4* p3 = (const float4*)(mfeat + (size_t)i3 * 64 + q * 8);
            float4 u0 = p0[0], v0 = p0[1];
            float4 u1 = p1[0], v1 = p1[1];
            float4 u2 = p2[0], v2 = p2[1];
            float4 u3 = p3[0], v3 = p3[1];
            ACC8(u0, v0); ACC8(u1, v1); ACC8(u2, v2); ACC8(u3, v3);
        }
        for (; e < e1; ++e) {
            const float4* p = (const float4*)(mfeat + (size_t)listm[e] * 64 + q * 8);
            float4 u = p[0], v = p[1];
            ACC8(u, v);
        }
        #undef ACC8
        {
            bf16x8 hi;
            #pragma unroll
            for (int i = 0; i < 8; ++i) hi[i] = f2bf(a[i]);
            *(bf16x8*)(xhi + r * 640 + ((464 + q * 16) ^ SWZ(r))) = hi;
        }
    }
    // --- zero pad cols 296..319 (essential: stale LDS can decode as bf16 Inf/NaN) ---
    if (tid < 192) {
        short4 z = { 0, 0, 0, 0 };
        int r = tid / 6, j = tid % 6;
        *(short4*)(xhi + r * 640 + ((592 + j * 8) ^ SWZ(r))) = z;
    }
    // --- stage edge indices ---
    #pragma unroll
    for (int it = 0; it < 4; ++it) {
        int idx = it * 256 + tid;
        int r = idx >> 5, j = idx & 31;
        eind[r * 33 + j] = edge_ind[(size_t)(n0 + r) * 32 + j];
    }
    __syncthreads();

    // --- edge attention (online softmax, LDS eind — load-bearing) ---
    {
        int r = tid & 31, h = tid >> 5;
        float qv = bf2f(qmh[(size_t)(n0 + r) * 8 + h]);
        float m = -INFINITY, s = 0.f, wv = 0.f;
        for (int j = 0; j < K_EDGE; ++j) {
            int e = eind[r * 33 + j];
            float v = bf2f(kmh[(size_t)e * 8 + h]);
            float l = qv * v;
            float mn = fmaxf(m, l);
            float fac = __expf(m - mn);
            float p = __expf(l - mn);
            s = s * fac + p;
            wv = wv * fac + p * v;
            m = mn;
        }
        *(short*)(xhi + r * 640 + ((320 + h * 2) ^ SWZ(r))) = f2bf(wv / s);
    }
    __syncthreads();

    // --- h1 = relu(x @ W1 + b1), 2-pass split MFMA: M=32, N=256, K=320 ---
    int wid = tid >> 6, lane = tid & 63;
    int arow = lane & 15, kgrp = lane >> 4;
    f32x4 c1[2][4];
    #pragma unroll
    for (int mt = 0; mt < 2; ++mt)
        #pragma unroll
        for (int nt = 0; nt < 4; ++nt)
            c1[mt][nt] = (f32x4){0.f, 0.f, 0.f, 0.f};
    const bf16x8* w1h = (const bf16x8*)W1Fh;
    const bf16x8* w1l = (const bf16x8*)W1Fl;
    for (int s = 0; s < 10; ++s) {
        int kb = (s * 32 + kgrp * 8) * 2;
        bf16x8 ahv[2], bh[4], bl[4];
        #pragma unroll
        for (int mt = 0; mt < 2; ++mt) {
            int rr = mt * 16 + arow;
            ahv[mt] = *(const bf16x8*)(xhi + rr * 640 + (kb ^ SWZ(rr)));
        }
        #pragma unroll
        for (int nt = 0; nt < 4; ++nt) {
            size_t fi = ((size_t)(wid * 4 + nt) * 10 + s) * 64 + lane;
            bh[nt] = w1h[fi];
            bl[nt] = w1l[fi];
        }
        #pragma unroll
        for (int mt = 0; mt < 2; ++mt)
            #pragma unroll
            for (int nt = 0; nt < 4; ++nt) {
                c1[mt][nt] = __builtin_amdgcn_mfma_f32_16x16x32_bf16(ahv[mt], bh[nt], c1[mt][nt], 0, 0, 0);
                c1[mt][nt] = __builtin_amdgcn_mfma_f32_16x16x32_bf16(ahv[mt], bl[nt], c1[mt][nt], 0, 0, 0);
            }
    }
    __syncthreads();
    // store h1 SINGLE bf16 plane [32][256], stride 512B
    char* h1p = buf;
    #pragma unroll
    for (int nt = 0; nt < 4; ++nt) {
        int col = wid * 64 + nt * 16 + arow;
        float bb = b1[col];
        #pragma unroll
        for (int mt = 0; mt < 2; ++mt)
            #pragma unroll
            for (int i = 0; i < 4; ++i) {
                int rr = mt * 16 + kgrp * 4 + i;
                float v = fmaxf(c1[mt][nt][i] + bb, 0.f);
                *(short*)(h1p + rr * 512 + ((col * 2) ^ SWZ(rr))) = f2bf(v);
            }
    }
    __syncthreads();

    // --- h2 = relu(h1 @ W2 + b2), 2-pass split MFMA: M=32, N=128, K=256 ---
    f32x4 c2[2][2];
    #pragma unroll
    for (int mt = 0; mt < 2; ++mt)
        #pragma unroll
        for (int nt = 0; nt < 2; ++nt)
            c2[mt][nt] = (f32x4){0.f, 0.f, 0.f, 0.f};
    const bf16x8* w2h = (const bf16x8*)W2Fh;
    const bf16x8* w2l = (const bf16x8*)W2Fl;
    for (int s = 0; s < 8; ++s) {
        int kb = (s * 32 + kgrp * 8) * 2;
        bf16x8 ahv[2], bh[2], bl[2];
        #pragma unroll
        for (int mt = 0; mt < 2; ++mt) {
            int rr = mt * 16 + arow;
            ahv[mt] = *(const bf16x8*)(h1p + rr * 512 + (kb ^ SWZ(rr)));
        }
        #pragma unroll
        for (int nt = 0; nt < 2; ++nt) {
            size_t fi = ((size_t)(wid * 2 + nt) * 8 + s) * 64 + lane;
            bh[nt] = w2h[fi];
            bl[nt] = w2l[fi];
        }
        #pragma unroll
        for (int mt = 0; mt < 2; ++mt)
            #pragma unroll
            for (int nt = 0; nt < 2; ++nt) {
                c2[mt][nt] = __builtin_amdgcn_mfma_f32_16x16x32_bf16(ahv[mt], bh[nt], c2[mt][nt], 0, 0, 0);
                c2[mt][nt] = __builtin_amdgcn_mfma_f32_16x16x32_bf16(ahv[mt], bl[nt], c2[mt][nt], 0, 0, 0);
            }
    }
    __syncthreads();
    // store h2 f32 [32][132], stride 528B
    #pragma unroll
    for (int nt = 0; nt < 2; ++nt) {
        int col = wid * 32 + nt * 16 + arow;
        float bb = b2[col];
        #pragma unroll
        for (int mt = 0; mt < 2; ++mt)
            #pragma unroll
            for (int i = 0; i < 4; ++i) {
                int rr = mt * 16 + kgrp * 4 + i;
                *(float*)(buf + rr * 528 + col * 4) = fmaxf(c2[mt][nt][i] + bb, 0.f);
            }
    }
    __syncthreads();

    // --- LayerNorm stats: 8 threads per row ---
    {
        int r = tid >> 3, q = tid & 7;
        const float* row = (const float*)(buf + r * 528) + q * 16;
        float s = 0.f, sq = 0.f;
        #pragma unroll
        for (int j = 0; j < 4; ++j) {
            float4 v = *(const float4*)(row + j * 4);
            s  += v.x + v.y + v.z + v.w;
            sq += v.x * v.x + v.y * v.y + v.z * v.z + v.w * v.w;
        }
        s  += __shfl_xor(s, 1);  sq += __shfl_xor(sq, 1);
        s  += __shfl_xor(s, 2);  sq += __shfl_xor(sq, 2);
        s  += __shfl_xor(s, 4);  sq += __shfl_xor(sq, 4);
        if (q == 0) {
            float mean = s * (1.f / 128.f);
            float var = sq * (1.f / 128.f) - mean * mean;
            mrs[r] = mean;
            mrs[32 + r] = rsqrtf(var + LN_EPS);
        }
    }
    __syncthreads();
    // --- normalize + affine + coalesced store ---
    #pragma unroll
    for (int it = 0; it < 4; ++it) {
        int idx = it * 256 + tid;
        int r = idx >> 5, c4 = idx & 31;
        float4 v = *(const float4*)(buf + r * 528 + c4 * 16);
        float mu = mrs[r], rs = mrs[32 + r];
        float4 g = ((const float4*)ln_g)[c4];
        float4 bb = ((const float4*)ln_b)[c4];
        float4 o;
        o.x = (v.x - mu) * rs * g.x + bb.x;
        o.y = (v.y - mu) * rs * g.y + bb.y;
        o.z = (v.z - mu) * rs * g.z + bb.z;
        o.w = (v.w - mu) * rs * g.w + bb.w;
        ((float4*)out)[(size_t)(n0 + r) * 32 + c4] = o;
    }
}

extern "C" void kernel_launch(void* const* d_in, const int* in_sizes, int n_in,
                              void* d_out, int out_size, void* d_ws, size_t ws_size,
                              hipStream_t stream) {
    const float* nodes    = (const float*)d_in[0];
    const float* globals_ = (const float*)d_in[1];
    const int*   n_node   = (const int*)  d_in[2];
    const float* edges    = (const float*)d_in[3];
    const int*   edge_ind = (const int*)  d_in[4];
    const float* hfeat    = (const float*)d_in[5];
    const int*   hind     = (const int*)  d_in[6];
    const float* mfeat    = (const float*)d_in[7];
    const int*   mind     = (const int*)  d_in[8];
    const float* Wq       = (const float*)d_in[9];
    const float* bq       = (const float*)d_in[10];
    const float* Wk       = (const float*)d_in[11];
    const float* bk       = (const float*)d_in[12];
    const float* Wc       = (const float*)d_in[13];
    const float* bc       = (const float*)d_in[14];
    const float* W1       = (const float*)d_in[15];
    const float* b1       = (const float*)d_in[16];
    const float* W2       = (const float*)d_in[17];
    const float* b2       = (const float*)d_in[18];
    const float* ln_g     = (const float*)d_in[19];
    const float* ln_b     = (const float*)d_in[20];
    float* out = (float*)d_out;

    char* w = (char*)d_ws;
    size_t off = 0;
    auto take = [&](size_t bytes) -> char* {
        char* p = w + off;
        off = (off + bytes + 255) & ~(size_t)255;
        return p;
    };
    float*    Wqc  = (float*)take(1024 * 4);
    float*    bqc  = (float*)take(8 * 4);
    float*    Wkc  = (float*)take(1024 * 4);
    float*    bkc  = (float*)take(8 * 4);
    short*    W1Fh = (short*)take(256 * KX * 2);
    short*    W1Fl = (short*)take(256 * KX * 2);
    short*    W2Fh = (short*)take(128 * 256 * 2);
    short*    W2Fl = (short*)take(128 * 256 * 2);
    ushort_t* kmh  = (ushort_t*)take((size_t)N_E * 8 * 2);
    ushort_t* qmh  = (ushort_t*)take((size_t)N_NODES * 8 * 2);
    int*      cnth = (int*)take((size_t)N_NODES * 4);
    int*      cntm = (int*)take((size_t)N_NODES * 4);   // contiguous with cnth
    int*      offh = (int*)take((size_t)N_NODES * 4);
    int*      woffh= (int*)take((size_t)N_NODES * 4);
    int*      offm = (int*)take((size_t)N_NODES * 4);
    int*      woffm= (int*)take((size_t)N_NODES * 4);
    int*      listh= (int*)take((size_t)HK3 * 4);
    int*      listm= (int*)take((size_t)N_M * 4);
    int*      bsum = (int*)take(2 * NCH * 4);
    (void)ws_size;

    prep_weights<<<5, 256, 0, stream>>>(Wq, bq, Wk, bk, Wc, bc, Wqc, bqc, Wkc, bkc);
    prep_wF<<<56, 256, 0, stream>>>(W1, W2, W1Fh, W1Fl, W2Fh, W2Fl);
    zero_ints<<<512, 256, 0, stream>>>(cnth, 2 * N_NODES);   // cnth+cntm contiguous
    aux1_kernel<<<NB_E + NB_N + NB_C, 256, 0, stream>>>(
        edges, Wkc, bkc, kmh, nodes, Wqc, bqc, qmh, hind, mind, cnth, cntm);
    sum_chunks<<<2 * NCH, 256, 0, stream>>>(cnth, cntm, bsum);
    scan_sums<<<1, 256, 0, stream>>>(bsum);
    scan_chunks<<<2 * NCH, 256, 0, stream>>>(cnth, cntm, bsum, offh, woffh, offm, woffm);
    fill_kernel<<<(HK3 / 4 + N_M / 4 + 255) / 256, 256, 0, stream>>>(
        hind, mind, woffh, woffm, listh, listm);
    main_kernel<<<N_NODES / TILE, 256, 0, stream>>>(
        nodes, globals_, n_node, edge_ind, kmh, qmh,
        hfeat, offh, woffh, listh, mfeat, offm, woffm, listm,
        W1Fh, W1Fl, b1, W2Fh, W2Fl, b2, ln_g, ln_b, out);
}